// Round 16
// baseline (814.334 us; speedup 1.0000x reference)
//
#include <hip/hip_runtime.h>
#include <math.h>

#define N_NODES 20000
#define N_EDGES 320000
#define D_IN    3072

#define M_PAD   20096   // 157 * 128
#define N1_PAD  1024
#define LDH1    1024
#define K2_PAD  1024
#define N2_PAD  384
#define LDH2    384

typedef short bf16x8 __attribute__((ext_vector_type(8)));
typedef float f32x4  __attribute__((ext_vector_type(4)));
typedef int   i32x4  __attribute__((ext_vector_type(4)));

#define GLOAD_LDS16(g, l) __builtin_amdgcn_global_load_lds( \
    (const __attribute__((address_space(1))) void*)(g),     \
    (__attribute__((address_space(3))) void*)(l), 16, 0, 0)

__device__ inline unsigned short f2bf(float x) {
    union { float f; unsigned u; } v; v.f = x;
    unsigned r = (v.u + 0x7FFFu + ((v.u >> 16) & 1u)) >> 16;
    return (unsigned short)r;
}
__device__ inline float bf2f(unsigned short h) {
    union { float f; unsigned u; } v; v.u = ((unsigned)h) << 16;
    return v.f;
}

// ---------------- CSR build ----------------

__global__ void zero_counts_kernel(int* __restrict__ counts) {
    int i = blockIdx.x * blockDim.x + threadIdx.x;
    if (i < N_NODES) counts[i] = 0;
}

__global__ void count_kernel(const int* __restrict__ dst, int* __restrict__ counts) {
    int e = blockIdx.x * blockDim.x + threadIdx.x;
    if (e < N_EDGES) atomicAdd(&counts[dst[e]], 1);
}

__global__ void scan_kernel(const int* __restrict__ counts, int* __restrict__ row_start,
                            int* __restrict__ cursor) {
    __shared__ int part[1024];
    const int T = 1024;
    int t = threadIdx.x;
    const int chunk = (N_NODES + T - 1) / T;
    int lo = t * chunk;
    int hi = lo + chunk; if (hi > N_NODES) hi = N_NODES;
    int s = 0;
    for (int i = lo; i < hi; ++i) s += counts[i];
    part[t] = s;
    __syncthreads();
    for (int off = 1; off < T; off <<= 1) {
        int v = (t >= off) ? part[t - off] : 0;
        __syncthreads();
        part[t] += v;
        __syncthreads();
    }
    int run = part[t] - s;
    for (int i = lo; i < hi; ++i) {
        row_start[i] = run;
        cursor[i] = run;
        run += counts[i];
    }
    if (t == T - 1) row_start[N_NODES] = run;
}

__global__ void scatter_kernel(const int* __restrict__ src, const int* __restrict__ dst,
                               int* __restrict__ cursor, int* __restrict__ esrc) {
    int e = blockIdx.x * blockDim.x + threadIdx.x;
    if (e < N_EDGES) {
        int pos = atomicAdd(&cursor[dst[e]], 1);
        esrc[pos] = src[e];
    }
}

// ---------------- i8 quantization ----------------
// a = s * (128*q1 + q2), |q| <= 16256 = 127*128, q2 in [-64,63].

__global__ __launch_bounds__(256)
void convA_i8_kernel(const float* __restrict__ X, signed char* __restrict__ Aq1,
                     signed char* __restrict__ Aq2, float* __restrict__ sA) {
    __shared__ float red[256];
    const int row = blockIdx.x;
    const int t = threadIdx.x;
    const float* xr = X + (size_t)row * D_IN;
    float v[12];
    float mx = 0.f;
    #pragma unroll
    for (int c = 0; c < 3; ++c) {
        float4 f = *reinterpret_cast<const float4*>(&xr[(t + c * 256) * 4]);
        v[c*4+0] = f.x; v[c*4+1] = f.y; v[c*4+2] = f.z; v[c*4+3] = f.w;
        mx = fmaxf(mx, fmaxf(fmaxf(fabsf(f.x), fabsf(f.y)), fmaxf(fabsf(f.z), fabsf(f.w))));
    }
    red[t] = mx;
    __syncthreads();
    for (int off = 128; off > 0; off >>= 1) {
        if (t < off) red[t] = fmaxf(red[t], red[t + off]);
        __syncthreads();
    }
    const float rmax = red[0];
    const float s   = (rmax > 0.f) ? rmax / 16256.f : 1.f;
    const float inv = 16256.f / ((rmax > 0.f) ? rmax : 1.f);
    if (t == 0) sA[row] = s;
    #pragma unroll
    for (int c = 0; c < 3; ++c) {
        signed char q1v[4], q2v[4];
        #pragma unroll
        for (int e = 0; e < 4; ++e) {
            int q = __float2int_rn(v[c*4+e] * inv);
            q = min(max(q, -16256), 16256);
            int q1 = (q + 64) >> 7;
            int q2 = q - (q1 << 7);
            q1v[e] = (signed char)q1; q2v[e] = (signed char)q2;
        }
        size_t base = (size_t)row * D_IN + (size_t)(t + c * 256) * 4;
        *reinterpret_cast<char4*>(&Aq1[base]) = make_char4(q1v[0], q1v[1], q1v[2], q1v[3]);
        *reinterpret_cast<char4*>(&Aq2[base]) = make_char4(q2v[0], q2v[1], q2v[2], q2v[3]);
    }
}

// ---- fused W quantization (r16): one block per 32 cols; in-block col-max,
// then quantize + LDS-transpose. Replaces zero/colmax/finalize/convW chains. ----

__global__ __launch_bounds__(256)
void quantW_i8_kernel(const float* __restrict__ W, signed char* __restrict__ Wq1T,
                      signed char* __restrict__ Wq2T, float* __restrict__ sW,
                      int K, int N, int K_PAD) {
    __shared__ float red[8][32];
    __shared__ float sh[32][33];
    __shared__ float sinv[32];
    const int t  = threadIdx.x;
    const int tx = t & 31;          // col within block
    const int kr = t >> 5;          // 0..7
    const int n0 = blockIdx.x * 32;
    const int n  = n0 + tx;
    // pass 1: column max (coalesced across n)
    float mx = 0.f;
    if (n < N)
        for (int k = kr; k < K; k += 8)
            mx = fmaxf(mx, fabsf(W[(size_t)k * N + n]));
    red[kr][tx] = mx;
    __syncthreads();
    if (kr == 0) {
        float m = red[0][tx];
        #pragma unroll
        for (int r = 1; r < 8; ++r) m = fmaxf(m, red[r][tx]);
        sW[n] = (m > 0.f) ? m / 16256.f : 1.f;
        sinv[tx] = 16256.f / ((m > 0.f) ? m : 1.f);
    }
    __syncthreads();
    // pass 2: quantize + transpose in 32x32 tiles
    for (int k0 = 0; k0 < K_PAD; k0 += 32) {
        #pragma unroll
        for (int it = 0; it < 4; ++it) {
            int k = k0 + kr + it * 8;
            sh[kr + it * 8][tx] = (k < K && n < N) ? W[(size_t)k * N + n] : 0.f;
        }
        __syncthreads();
        #pragma unroll
        for (int it = 0; it < 4; ++it) {
            int nn = n0 + kr + it * 8;      // output row (col of W)
            int k  = k0 + tx;
            float v = sh[tx][kr + it * 8];
            float inv = sinv[kr + it * 8];
            int q = __float2int_rn(v * inv);
            q = min(max(q, -16256), 16256);
            int q1 = (q + 64) >> 7;
            int q2 = q - (q1 << 7);
            Wq1T[(size_t)nn * K_PAD + k] = (signed char)q1;
            Wq2T[(size_t)nn * K_PAD + k] = (signed char)q2;
        }
        __syncthreads();
    }
}

// ---------------- i8 MFMA GEMM: 3-term, 16x16x64 ----------------
// H = sA[m]*sW[n]*(16384*accH + 128*accM) + bias; OUTBF: 1 -> bf16 out, 0 -> f32.
// r10-verified schedule. launch_bounds(256,2): r13/r15-proven VGPR 104, zero spill.
// (256,3) caps the allocator below the 128-reg accumulator state -> spill (r14).

#define GBM 128
#define GBN 128

#define ISSUE2I(p0, p1, ss) do { \
    GLOAD_LDS16(p0, &lds[ss][wid * 1024]); \
    GLOAD_LDS16(p1, &lds[ss][wid * 1024 + 4096]); \
    p0 += 64; p1 += 64; } while (0)

template <int OUTBF>
__global__ __launch_bounds__(256, 2)
void gemm_i8_mfma_kernel(const signed char* __restrict__ Aq1,
                         const signed char* __restrict__ Aq2,
                         const signed char* __restrict__ Bq1T,
                         const signed char* __restrict__ Bq2T,
                         const float* __restrict__ sA, const float* __restrict__ sB,
                         const float* __restrict__ bias, void* __restrict__ Hout,
                         int K, int NB, int ldh, int nbias) {
    __shared__ __align__(16) char lds[4][8192];

    const int t    = threadIdx.x;
    const int wid  = t >> 6;
    const int lane = t & 63;
    const int wr   = wid >> 1;
    const int wc   = wid & 1;

    const int orig = blockIdx.x;
    const int nwg  = gridDim.x;
    const int xcd  = orig & 7, loc = orig >> 3;
    const int q    = nwg >> 3, r = nwg & 7;
    const int wgid = (xcd < r ? xcd * (q + 1) : r * (q + 1) + (xcd - r) * q) + loc;
    const int m0   = (wgid / NB) * GBM;
    const int n0   = (wgid % NB) * GBN;

    i32x4 accH[4][4] = {};
    i32x4 accM[4][4] = {};

    const int byt0 = wid * 1024 + lane * 16;
    const int byt1 = byt0 + 4096;
    const int r0 = byt0 >> 6, r1 = byt1 >> 6;
    const int cs0 = (byt0 & 63) ^ (((r0 >> 1) & 3) << 4);
    const int cs1 = (byt1 & 63) ^ (((r1 >> 1) & 3) << 4);

    const signed char* pA10 = Aq1  + (size_t)(m0 + r0) * K + cs0;
    const signed char* pA11 = Aq1  + (size_t)(m0 + r1) * K + cs1;
    const signed char* pA20 = Aq2  + (size_t)(m0 + r0) * K + cs0;
    const signed char* pA21 = Aq2  + (size_t)(m0 + r1) * K + cs1;
    const signed char* pB10 = Bq1T + (size_t)(n0 + r0) * K + cs0;
    const signed char* pB11 = Bq1T + (size_t)(n0 + r1) * K + cs1;
    const signed char* pB20 = Bq2T + (size_t)(n0 + r0) * K + cs0;
    const signed char* pB21 = Bq2T + (size_t)(n0 + r1) * K + cs1;

    const int fr   = lane & 15;
    const int kbs  = ((lane >> 4) << 4) ^ (((fr >> 1) & 3) << 4);
    const int arow = wr * 64;
    const int brow = wc * 64;

    ISSUE2I(pA10, pA11, 0);
    ISSUE2I(pB10, pB11, 2);
    ISSUE2I(pB20, pB21, 3);
    ISSUE2I(pA20, pA21, 1);

    const int NT = K >> 6;
    i32x4 a1[4], b1[4], b2[4], a2[4];

    for (int tt = 0; tt < NT; ++tt) {
        // ---- phase 1: A1*B1 -> accH ----
        if (tt == 0) asm volatile("s_waitcnt vmcnt(4)" ::: "memory");
        else         asm volatile("s_waitcnt vmcnt(2)" ::: "memory");
        __builtin_amdgcn_s_barrier();
        #pragma unroll
        for (int i = 0; i < 4; ++i)
            a1[i] = *(const i32x4*)(&lds[0][(arow + i * 16 + fr) * 64 + kbs]);
        #pragma unroll
        for (int j = 0; j < 4; ++j)
            b1[j] = *(const i32x4*)(&lds[2][(brow + j * 16 + fr) * 64 + kbs]);
        if (tt > 0) ISSUE2I(pA20, pA21, 1);
        __builtin_amdgcn_s_setprio(1);
        #pragma unroll
        for (int i = 0; i < 4; ++i)
            #pragma unroll
            for (int j = 0; j < 4; ++j)
                accH[i][j] = __builtin_amdgcn_mfma_i32_16x16x64_i8(a1[i], b1[j], accH[i][j], 0, 0, 0);
        __builtin_amdgcn_s_setprio(0);
        // ---- phase 2: A1*B2 -> accM ----
        asm volatile("s_waitcnt vmcnt(2)" ::: "memory");
        __builtin_amdgcn_s_barrier();
        #pragma unroll
        for (int j = 0; j < 4; ++j)
            b2[j] = *(const i32x4*)(&lds[3][(brow + j * 16 + fr) * 64 + kbs]);
        if (tt < NT - 1) {
            ISSUE2I(pA10, pA11, 0);
            ISSUE2I(pB10, pB11, 2);
        }
        __builtin_amdgcn_s_setprio(1);
        #pragma unroll
        for (int i = 0; i < 4; ++i)
            #pragma unroll
            for (int j = 0; j < 4; ++j)
                accM[i][j] = __builtin_amdgcn_mfma_i32_16x16x64_i8(a1[i], b2[j], accM[i][j], 0, 0, 0);
        __builtin_amdgcn_s_setprio(0);
        // ---- phase 3: A2*B1 -> accM ----
        if (tt < NT - 1) asm volatile("s_waitcnt vmcnt(4)" ::: "memory");
        else             asm volatile("s_waitcnt vmcnt(0)" ::: "memory");
        __builtin_amdgcn_s_barrier();
        #pragma unroll
        for (int i = 0; i < 4; ++i)
            a2[i] = *(const i32x4*)(&lds[1][(arow + i * 16 + fr) * 64 + kbs]);
        if (tt < NT - 1) ISSUE2I(pB20, pB21, 3);
        __builtin_amdgcn_s_setprio(1);
        #pragma unroll
        for (int i = 0; i < 4; ++i)
            #pragma unroll
            for (int j = 0; j < 4; ++j)
                accM[i][j] = __builtin_amdgcn_mfma_i32_16x16x64_i8(a2[i], b1[j], accM[i][j], 0, 0, 0);
        __builtin_amdgcn_s_setprio(0);
    }

    // epilogue: C layout col = lane&15, row = (lane>>4)*4 + reg
    #pragma unroll
    for (int i = 0; i < 4; ++i) {
        #pragma unroll
        for (int j = 0; j < 4; ++j) {
            int row = m0 + wr * 64 + i * 16 + (lane >> 4) * 4;
            int col = n0 + wc * 64 + j * 16 + (lane & 15);
            float bv = (col < nbias) ? bias[col] : 0.f;
            float sw = sB[col];
            #pragma unroll
            for (int r2 = 0; r2 < 4; ++r2) {
                float sa = sA[row + r2];
                float v = sa * sw * (16384.f * (float)accH[i][j][r2] + 128.f * (float)accM[i][j][r2]) + bv;
                if (OUTBF) ((unsigned short*)Hout)[(size_t)(row + r2) * ldh + col] = f2bf(v);
                else       ((float*)Hout)[(size_t)(row + r2) * ldh + col] = v;
            }
        }
    }
}

// ---------------- fp32 tiled GEMM (fallback path only) ----------------

#define BM 64
#define BN 64
#define BKT 16
#define TM 4
#define TN 4

__global__ __launch_bounds__(256)
void gemm_bias_kernel(const float* __restrict__ X, const float* __restrict__ W,
                      const float* __restrict__ bias, float* __restrict__ H,
                      int M, int N, int K) {
    __shared__ float As[BKT][BM];
    __shared__ float Bs[BKT][BN];

    const int t  = threadIdx.x;
    const int tx = t & 15;
    const int ty = t >> 4;
    const int m0 = blockIdx.y * BM;
    const int n0 = blockIdx.x * BN;

    float acc[TM][TN] = {};

    const int arow = t >> 2;
    const int ak0  = (t & 3) * 4;
    const int brow = t >> 4;
    const int bn0  = (t & 15) * 4;

    for (int k0 = 0; k0 < K; k0 += BKT) {
        {
            float4 v = make_float4(0.f, 0.f, 0.f, 0.f);
            int gm = m0 + arow;
            int gk = k0 + ak0;
            if (gm < M) {
                if (gk + 3 < K) {
                    v = *reinterpret_cast<const float4*>(&X[(long)gm * K + gk]);
                } else {
                    float tmp[4] = {0.f, 0.f, 0.f, 0.f};
                    for (int i = 0; i < 4; ++i)
                        if (gk + i < K) tmp[i] = X[(long)gm * K + gk + i];
                    v = make_float4(tmp[0], tmp[1], tmp[2], tmp[3]);
                }
            }
            As[ak0 + 0][arow] = v.x;
            As[ak0 + 1][arow] = v.y;
            As[ak0 + 2][arow] = v.z;
            As[ak0 + 3][arow] = v.w;
        }
        {
            float4 v = make_float4(0.f, 0.f, 0.f, 0.f);
            int gk = k0 + brow;
            int gn = n0 + bn0;
            if (gk < K) {
                if (gn + 3 < N) {
                    v = *reinterpret_cast<const float4*>(&W[(long)gk * N + gn]);
                } else {
                    float tmp[4] = {0.f, 0.f, 0.f, 0.f};
                    for (int i = 0; i < 4; ++i)
                        if (gn + i < N) tmp[i] = W[(long)gk * N + gn + i];
                    v = make_float4(tmp[0], tmp[1], tmp[2], tmp[3]);
                }
            }
            *reinterpret_cast<float4*>(&Bs[brow][bn0]) = v;
        }
        __syncthreads();

        #pragma unroll
        for (int kk = 0; kk < BKT; ++kk) {
            float a[TM], b[TN];
            *reinterpret_cast<float4*>(a) = *reinterpret_cast<const float4*>(&As[kk][ty * TM]);
            *reinterpret_cast<float4*>(b) = *reinterpret_cast<const float4*>(&Bs[kk][tx * TN]);
            #pragma unroll
            for (int i = 0; i < TM; ++i)
                #pragma unroll
                for (int j = 0; j < TN; ++j)
                    acc[i][j] += a[i] * b[j];
        }
        __syncthreads();
    }

    #pragma unroll
    for (int i = 0; i < TM; ++i) {
        int gm = m0 + ty * TM + i;
        if (gm >= M) continue;
        #pragma unroll
        for (int j = 0; j < TN; ++j) {
            int gn = n0 + tx * TN + j;
            if (gn < N) H[(long)gm * N + gn] = acc[i][j] + bias[gn];
        }
    }
}

// ---------------- aggregates ----------------

// layer-1 aggregate: reads bf16 H1, relu, fused i8 quantize (block-max scheme)
__global__ __launch_bounds__(256)
void aggregate_i8_kernel(const unsigned short* __restrict__ H1,
                         const int* __restrict__ row_start, const int* __restrict__ esrc,
                         signed char* __restrict__ Xq1, signed char* __restrict__ Xq2,
                         float* __restrict__ sX, int d, int ld_in, int kpad) {
    __shared__ float red[256];
    const int node = blockIdx.x;
    const int t = threadIdx.x;
    const int f = t * 4;
    const int beg = row_start[node];
    const int end = row_start[node + 1];

    float a[4] = {0.f, 0.f, 0.f, 0.f};
    if (f < d) {
        ushort4 v = *reinterpret_cast<const ushort4*>(&H1[(size_t)node * ld_in + f]);
        a[0] = bf2f(v.x); a[1] = bf2f(v.y); a[2] = bf2f(v.z); a[3] = bf2f(v.w);
        for (int i = beg; i < end; ++i) {
            ushort4 w = *reinterpret_cast<const ushort4*>(&H1[(size_t)esrc[i] * ld_in + f]);
            a[0] += bf2f(w.x); a[1] += bf2f(w.y); a[2] += bf2f(w.z); a[3] += bf2f(w.w);
        }
        a[0] = fmaxf(a[0], 0.f); a[1] = fmaxf(a[1], 0.f);
        a[2] = fmaxf(a[2], 0.f); a[3] = fmaxf(a[3], 0.f);
    }
    float mx = fmaxf(fmaxf(a[0], a[1]), fmaxf(a[2], a[3]));
    red[t] = mx;
    __syncthreads();
    for (int off = 128; off > 0; off >>= 1) {
        if (t < off) red[t] = fmaxf(red[t], red[t + off]);
        __syncthreads();
    }
    const float rmax = red[0];
    const float s   = (rmax > 0.f) ? rmax / 16256.f : 1.f;
    const float inv = 16256.f / ((rmax > 0.f) ? rmax : 1.f);
    if (t == 0) sX[node] = s;
    if (f < kpad) {
        signed char q1v[4], q2v[4];
        #pragma unroll
        for (int e = 0; e < 4; ++e) {
            int q = (f < d) ? __float2int_rn(a[e] * inv) : 0;
            q = min(max(q, 0), 16256);
            int q1 = (q + 64) >> 7;
            int q2 = q - (q1 << 7);
            q1v[e] = (signed char)q1; q2v[e] = (signed char)q2;
        }
        *reinterpret_cast<char4*>(&Xq1[(size_t)node * kpad + f]) = make_char4(q1v[0], q1v[1], q1v[2], q1v[3]);
        *reinterpret_cast<char4*>(&Xq2[(size_t)node * kpad + f]) = make_char4(q2v[0], q2v[1], q2v[2], q2v[3]);
    }
}

// fused: x3 = relu(agg(H2 bf16, d=300)) in LDS; h3 = x3 @ W3[300,20] + b3
__global__ __launch_bounds__(128)
void agg2_gemm3_kernel(const unsigned short* __restrict__ H2, const int* __restrict__ row_start,
                       const int* __restrict__ esrc, const float* __restrict__ W3,
                       const float* __restrict__ b3, float* __restrict__ h3) {
    __shared__ float x3s[304];
    __shared__ float part[6][20];
    const int node = blockIdx.x;
    const int t = threadIdx.x;
    const int beg = row_start[node];
    const int end = row_start[node + 1];
    if (t < 75) {
        const int f = t * 4;
        ushort4 v = *reinterpret_cast<const ushort4*>(&H2[(size_t)node * LDH2 + f]);
        float a0 = bf2f(v.x), a1 = bf2f(v.y), a2 = bf2f(v.z), a3 = bf2f(v.w);
        for (int i = beg; i < end; ++i) {
            ushort4 w = *reinterpret_cast<const ushort4*>(&H2[(size_t)esrc[i] * LDH2 + f]);
            a0 += bf2f(w.x); a1 += bf2f(w.y); a2 += bf2f(w.z); a3 += bf2f(w.w);
        }
        x3s[f + 0] = fmaxf(a0, 0.f);
        x3s[f + 1] = fmaxf(a1, 0.f);
        x3s[f + 2] = fmaxf(a2, 0.f);
        x3s[f + 3] = fmaxf(a3, 0.f);
    }
    __syncthreads();
    if (t < 120) {
        const int j = t % 20, g = t / 20;
        float s = 0.f;
        #pragma unroll 5
        for (int k = g * 50; k < g * 50 + 50; ++k)
            s += x3s[k] * W3[k * 20 + j];
        part[g][j] = s;
    }
    __syncthreads();
    if (t < 20) {
        float s = b3[t];
        #pragma unroll
        for (int g = 0; g < 6; ++g) s += part[g][t];
        h3[(size_t)node * 20 + t] = s;
    }
}

// fused: x4 = agg(h3, d=20) in LDS; h4 = x4 @ W4[20,10] + b4
__global__ __launch_bounds__(64)
void agg3_gemm4_kernel(const float* __restrict__ h3, const int* __restrict__ row_start,
                       const int* __restrict__ esrc, const float* __restrict__ W4,
                       const float* __restrict__ b4, float* __restrict__ h4) {
    __shared__ float x4s[20];
    const int node = blockIdx.x;
    const int t = threadIdx.x;
    const int beg = row_start[node];
    const int end = row_start[node + 1];
    if (t < 20) {
        float acc = h3[(size_t)node * 20 + t];
        for (int i = beg; i < end; ++i)
            acc += h3[(size_t)esrc[i] * 20 + t];
        x4s[t] = acc;
    }
    __syncthreads();
    if (t < 10) {
        float s = b4[t];
        #pragma unroll
        for (int k = 0; k < 20; ++k) s += x4s[k] * W4[k * 10 + t];
        h4[(size_t)node * 10 + t] = s;
    }
}

template <int ACT>
__global__ __launch_bounds__(64)
void aggregate_small_kernel(const float* __restrict__ H, const int* __restrict__ row_start,
                            const int* __restrict__ esrc, float* __restrict__ out,
                            int d, int ld_in, int ld_out) {
    const int node = blockIdx.x;
    const int f = threadIdx.x;
    if (f >= d) return;
    const int beg = row_start[node];
    const int end = row_start[node + 1];
    float acc = H[(size_t)node * ld_in + f];
    for (int i = beg; i < end; ++i)
        acc += H[(size_t)esrc[i] * ld_in + f];
    if (ACT == 1) acc = fmaxf(acc, 0.f);
    if (ACT == 2) acc = tanhf(acc);
    out[(size_t)node * ld_out + f] = acc;
}

template <int ACT>
__global__ __launch_bounds__(256)
void aggregate_kernel(const float* __restrict__ H, const int* __restrict__ row_start,
                      const int* __restrict__ esrc, float* __restrict__ out,
                      int d, int ld_in) {
    const int node = blockIdx.x;
    const int t = threadIdx.x;
    const int beg = row_start[node];
    const int end = row_start[node + 1];
    float acc[4] = {0.f, 0.f, 0.f, 0.f};
    #pragma unroll
    for (int j = 0; j < 4; ++j) {
        int f = t + j * 256;
        if (f < d) acc[j] = H[(size_t)node * ld_in + f];
    }
    for (int i = beg; i < end; ++i) {
        const size_t b = (size_t)esrc[i] * ld_in;
        #pragma unroll
        for (int j = 0; j < 4; ++j) {
            int f = t + j * 256;
            if (f < d) acc[j] += H[b + f];
        }
    }
    #pragma unroll
    for (int j = 0; j < 4; ++j) {
        int f = t + j * 256;
        if (f < d) {
            float v = acc[j];
            if (ACT == 1) v = fmaxf(v, 0.f);
            if (ACT == 2) v = tanhf(v);
            out[(size_t)node * d + f] = v;
        }
    }
}

// ---------------- launch ----------------

extern "C" void kernel_launch(void* const* d_in, const int* in_sizes, int n_in,
                              void* d_out, int out_size, void* d_ws, size_t ws_size,
                              hipStream_t stream) {
    const float* features = (const float*)d_in[0];
    const int*   src      = (const int*)d_in[1];
    const int*   dst      = (const int*)d_in[2];
    const float* W1 = (const float*)d_in[3];  const float* b1 = (const float*)d_in[4];
    const float* W2 = (const float*)d_in[5];  const float* b2 = (const float*)d_in[6];
    const float* W3 = (const float*)d_in[7];  const float* b3 = (const float*)d_in[8];
    const float* W4 = (const float*)d_in[9];  const float* b4 = (const float*)d_in[10];
    float* out = (float*)d_out;
    char* ws = (char*)d_ws;

    // ---- workspace map (~174 MB) ----
    const size_t SZ_AQ    = (size_t)M_PAD * D_IN;
    const size_t OFF_AQ1  = 0;
    const size_t OFF_AQ2  = SZ_AQ;
    const size_t OFF_H1   = 2 * SZ_AQ;
    const size_t SZ_H1    = (size_t)M_PAD * LDH1 * 2;       // bf16
    const size_t OFF_W1Q1 = OFF_H1 + SZ_H1;
    const size_t SZ_W1Q   = (size_t)N1_PAD * D_IN;
    const size_t OFF_W1Q2 = OFF_W1Q1 + SZ_W1Q;
    const size_t OFF_SA   = OFF_W1Q2 + SZ_W1Q;
    const size_t SZ_SA    = (size_t)M_PAD * 4;
    const size_t OFF_SW1  = OFF_SA + SZ_SA;
    const size_t OFF_W2Q1 = OFF_SW1 + 4096;
    const size_t SZ_W2Q   = (size_t)N2_PAD * K2_PAD;
    const size_t OFF_W2Q2 = OFF_W2Q1 + SZ_W2Q;
    const size_t OFF_SW2  = OFF_W2Q2 + SZ_W2Q;
    const size_t OFF_SA2  = OFF_SW2 + 4096;
    const size_t OFF_CSR  = OFF_SA2 + SZ_SA;
    const size_t SZ_CSR   = (size_t)(N_NODES * 3 + 1 + N_EDGES) * 4;
    const size_t WS_NEED  = OFF_CSR + SZ_CSR;

    const size_t OFF_X2Q1 = 0;
    const size_t SZ_X2Q   = (size_t)M_PAD * K2_PAD;
    const size_t OFF_X2Q2 = SZ_X2Q;
    const size_t OFF_H2   = 2 * SZ_X2Q;                     // bf16 H2 (15.4 MB)
    const size_t OFF_H3   = OFF_H1;
    const size_t OFF_H4   = OFF_H1 + 1600000;

    const bool use_mfma = (ws_size >= WS_NEED);
    size_t csr_off = use_mfma ? OFF_CSR : (size_t)2 * N_NODES * 1000 * 4;
    int* counts    = (int*)(ws + csr_off);
    int* row_start = counts + N_NODES;
    int* cursor    = row_start + N_NODES + 1;
    int* esrc      = cursor + N_NODES;

    zero_counts_kernel<<<(N_NODES + 255) / 256, 256, 0, stream>>>(counts);
    count_kernel<<<(N_EDGES + 255) / 256, 256, 0, stream>>>(dst, counts);
    scan_kernel<<<1, 1024, 0, stream>>>(counts, row_start, cursor);
    scatter_kernel<<<(N_EDGES + 255) / 256, 256, 0, stream>>>(src, dst, cursor, esrc);

    if (use_mfma) {
        signed char*    Aq1   = (signed char*)(ws + OFF_AQ1);
        signed char*    Aq2   = (signed char*)(ws + OFF_AQ2);
        unsigned short* H1    = (unsigned short*)(ws + OFF_H1);
        signed char*    W1q1T = (signed char*)(ws + OFF_W1Q1);
        signed char*    W1q2T = (signed char*)(ws + OFF_W1Q2);
        float*          sA    = (float*)(ws + OFF_SA);
        float*          sW1   = (float*)(ws + OFF_SW1);
        signed char*    W2q1T = (signed char*)(ws + OFF_W2Q1);
        signed char*    W2q2T = (signed char*)(ws + OFF_W2Q2);
        float*          sW2   = (float*)(ws + OFF_SW2);
        signed char*    X2q1  = (signed char*)(ws + OFF_X2Q1);
        signed char*    X2q2  = (signed char*)(ws + OFF_X2Q2);
        float*          sA2   = (float*)(ws + OFF_SA2);
        unsigned short* H2    = (unsigned short*)(ws + OFF_H2);
        float*          h3    = (float*)(ws + OFF_H3);
        float*          h4    = (float*)(ws + OFF_H4);

        // Layer 1: i8 3-term MFMA GEMM (16x16x64), bf16 H1 out
        convA_i8_kernel<<<N_NODES, 256, 0, stream>>>(features, Aq1, Aq2, sA);
        quantW_i8_kernel<<<N1_PAD / 32, 256, 0, stream>>>(W1, W1q1T, W1q2T, sW1, D_IN, 1000, D_IN);
        gemm_i8_mfma_kernel<1><<<(N1_PAD / GBN) * (M_PAD / GBM), 256, 0, stream>>>(
            Aq1, Aq2, W1q1T, W1q2T, sA, sW1, b1, H1, D_IN, N1_PAD / GBN, LDH1, 1000);
        aggregate_i8_kernel<<<N_NODES, 256, 0, stream>>>(
            H1, row_start, esrc, X2q1, X2q2, sA2, 1000, LDH1, K2_PAD);

        // Layer 2: i8 3-term MFMA GEMM, bf16 H2 out
        quantW_i8_kernel<<<N2_PAD / 32, 256, 0, stream>>>(W2, W2q1T, W2q2T, sW2, 1000, 300, K2_PAD);
        gemm_i8_mfma_kernel<1><<<(N2_PAD / GBN) * (M_PAD / GBM), 256, 0, stream>>>(
            X2q1, X2q2, W2q1T, W2q2T, sA2, sW2, b2, H2, K2_PAD, N2_PAD / GBN, LDH2, 300);

        // Layers 3+4 fused
        agg2_gemm3_kernel<<<N_NODES, 128, 0, stream>>>(H2, row_start, esrc, W3, b3, h3);
        agg3_gemm4_kernel<<<N_NODES, 64, 0, stream>>>(h3, row_start, esrc, W4, b4, h4);
        aggregate_small_kernel<2><<<N_NODES, 64, 0, stream>>>(h4, row_start, esrc, out, 10, 10, 10);
    } else {
        const size_t BUF = (size_t)N_NODES * 1000 * 4;
        float* bufA = (float*)ws;
        float* bufB = (float*)(ws + BUF);

        dim3 g1((1000 + BN - 1) / BN, (N_NODES + BM - 1) / BM);
        gemm_bias_kernel<<<g1, 256, 0, stream>>>(features, W1, b1, bufA, N_NODES, 1000, D_IN);
        aggregate_kernel<1><<<N_NODES, 256, 0, stream>>>(bufA, row_start, esrc, bufB, 1000, 1000);

        dim3 g2((300 + BN - 1) / BN, (N_NODES + BM - 1) / BM);
        gemm_bias_kernel<<<g2, 256, 0, stream>>>(bufB, W2, b2, bufA, N_NODES, 300, 1000);
        aggregate_kernel<1><<<N_NODES, 256, 0, stream>>>(bufA, row_start, esrc, bufB, 300, 300);

        dim3 g3((20 + BN - 1) / BN, (N_NODES + BM - 1) / BM);
        gemm_bias_kernel<<<g3, 256, 0, stream>>>(bufB, W3, b3, bufA, N_NODES, 20, 300);
        aggregate_kernel<0><<<N_NODES, 256, 0, stream>>>(bufA, row_start, esrc, bufB, 20, 20);

        dim3 g4((10 + BN - 1) / BN, (N_NODES + BM - 1) / BM);
        gemm_bias_kernel<<<g4, 256, 0, stream>>>(bufB, W4, b4, bufA, N_NODES, 10, 20);
        aggregate_kernel<2><<<N_NODES, 256, 0, stream>>>(bufA, row_start, esrc, out, 10, 10);
    }
}

// Round 17
// 659.172 us; speedup vs baseline: 1.2354x; 1.2354x over previous
//
#include <hip/hip_runtime.h>
#include <math.h>

#define N_NODES 20000
#define N_EDGES 320000
#define D_IN    3072

#define M_PAD   20096   // 157 * 128
#define N1_PAD  1024
#define LDH1    1024
#define K2_PAD  1024
#define N2_PAD  384
#define LDH2    384

typedef short bf16x8 __attribute__((ext_vector_type(8)));
typedef float f32x4  __attribute__((ext_vector_type(4)));
typedef int   i32x4  __attribute__((ext_vector_type(4)));

#define GLOAD_LDS16(g, l) __builtin_amdgcn_global_load_lds( \
    (const __attribute__((address_space(1))) void*)(g),     \
    (__attribute__((address_space(3))) void*)(l), 16, 0, 0)

__device__ inline unsigned short f2bf(float x) {
    union { float f; unsigned u; } v; v.f = x;
    unsigned r = (v.u + 0x7FFFu + ((v.u >> 16) & 1u)) >> 16;
    return (unsigned short)r;
}
__device__ inline float bf2f(unsigned short h) {
    union { float f; unsigned u; } v; v.u = ((unsigned)h) << 16;
    return v.f;
}

// ---------------- CSR build ----------------

__global__ void zero_counts_kernel(int* __restrict__ counts) {
    int i = blockIdx.x * blockDim.x + threadIdx.x;
    if (i < N_NODES) counts[i] = 0;
}

__global__ void count_kernel(const int* __restrict__ dst, int* __restrict__ counts) {
    int e = blockIdx.x * blockDim.x + threadIdx.x;
    if (e < N_EDGES) atomicAdd(&counts[dst[e]], 1);
}

__global__ void scan_kernel(const int* __restrict__ counts, int* __restrict__ row_start,
                            int* __restrict__ cursor) {
    __shared__ int part[1024];
    const int T = 1024;
    int t = threadIdx.x;
    const int chunk = (N_NODES + T - 1) / T;
    int lo = t * chunk;
    int hi = lo + chunk; if (hi > N_NODES) hi = N_NODES;
    int s = 0;
    for (int i = lo; i < hi; ++i) s += counts[i];
    part[t] = s;
    __syncthreads();
    for (int off = 1; off < T; off <<= 1) {
        int v = (t >= off) ? part[t - off] : 0;
        __syncthreads();
        part[t] += v;
        __syncthreads();
    }
    int run = part[t] - s;
    for (int i = lo; i < hi; ++i) {
        row_start[i] = run;
        cursor[i] = run;
        run += counts[i];
    }
    if (t == T - 1) row_start[N_NODES] = run;
}

__global__ void scatter_kernel(const int* __restrict__ src, const int* __restrict__ dst,
                               int* __restrict__ cursor, int* __restrict__ esrc) {
    int e = blockIdx.x * blockDim.x + threadIdx.x;
    if (e < N_EDGES) {
        int pos = atomicAdd(&cursor[dst[e]], 1);
        esrc[pos] = src[e];
    }
}

// ---------------- i8 quantization ----------------
// a = s * (128*q1 + q2), |q| <= 16256 = 127*128, q2 in [-64,63].

__global__ __launch_bounds__(256)
void convA_i8_kernel(const float* __restrict__ X, signed char* __restrict__ Aq1,
                     signed char* __restrict__ Aq2, float* __restrict__ sA) {
    __shared__ float red[256];
    const int row = blockIdx.x;
    const int t = threadIdx.x;
    const float* xr = X + (size_t)row * D_IN;
    float v[12];
    float mx = 0.f;
    #pragma unroll
    for (int c = 0; c < 3; ++c) {
        float4 f = *reinterpret_cast<const float4*>(&xr[(t + c * 256) * 4]);
        v[c*4+0] = f.x; v[c*4+1] = f.y; v[c*4+2] = f.z; v[c*4+3] = f.w;
        mx = fmaxf(mx, fmaxf(fmaxf(fabsf(f.x), fabsf(f.y)), fmaxf(fabsf(f.z), fabsf(f.w))));
    }
    red[t] = mx;
    __syncthreads();
    for (int off = 128; off > 0; off >>= 1) {
        if (t < off) red[t] = fmaxf(red[t], red[t + off]);
        __syncthreads();
    }
    const float rmax = red[0];
    const float s   = (rmax > 0.f) ? rmax / 16256.f : 1.f;
    const float inv = 16256.f / ((rmax > 0.f) ? rmax : 1.f);
    if (t == 0) sA[row] = s;
    #pragma unroll
    for (int c = 0; c < 3; ++c) {
        signed char q1v[4], q2v[4];
        #pragma unroll
        for (int e = 0; e < 4; ++e) {
            int q = __float2int_rn(v[c*4+e] * inv);
            q = min(max(q, -16256), 16256);
            int q1 = (q + 64) >> 7;
            int q2 = q - (q1 << 7);
            q1v[e] = (signed char)q1; q2v[e] = (signed char)q2;
        }
        size_t base = (size_t)row * D_IN + (size_t)(t + c * 256) * 4;
        *reinterpret_cast<char4*>(&Aq1[base]) = make_char4(q1v[0], q1v[1], q1v[2], q1v[3]);
        *reinterpret_cast<char4*>(&Aq2[base]) = make_char4(q2v[0], q2v[1], q2v[2], q2v[3]);
    }
}

// ---- column-max of |W|: r13/r15-proven parallel chain (r16's fused version
// launched only N/32 blocks -> 1.4% occupancy -> 228 us; keep the wide grid) ----

__global__ __launch_bounds__(256)
void zero_swbits_kernel(unsigned* __restrict__ bits, int NPAD) {
    int n = blockIdx.x * blockDim.x + threadIdx.x;
    if (n < NPAD) bits[n] = 0u;
}

__global__ __launch_bounds__(256)
void colmaxW_kernel(const float* __restrict__ W, unsigned* __restrict__ bits,
                    int K, int N, int KCHUNK) {
    int n = blockIdx.x * blockDim.x + threadIdx.x;
    if (n >= N) return;
    int k0 = blockIdx.y * KCHUNK;
    int k1 = min(k0 + KCHUNK, K);
    float mx = 0.f;
    for (int k = k0; k < k1; ++k)
        mx = fmaxf(mx, fabsf(W[(size_t)k * N + n]));
    atomicMax(&bits[n], __float_as_uint(mx));
}

__global__ __launch_bounds__(256)
void finalize_sw_kernel(unsigned* __restrict__ bits, float* __restrict__ sW, int NPAD) {
    int n = blockIdx.x * blockDim.x + threadIdx.x;
    if (n >= NPAD) return;
    float mx = __uint_as_float(bits[n]);
    sW[n] = (mx > 0.f) ? mx / 16256.f : 1.f;
}

// W [K][N] f32 -> Wq1T/Wq2T [NPAD][K_PAD] i8 (transposed, zero-padded)
__global__ __launch_bounds__(256)
void convW_i8_kernel(const float* __restrict__ W, const float* __restrict__ sW,
                     signed char* __restrict__ Wq1T, signed char* __restrict__ Wq2T,
                     int K, int N, int K_PAD) {
    __shared__ float sh[32][33];
    const int t  = threadIdx.x;
    const int tx = t & 31;
    const int ty = t >> 5;
    const int n0 = blockIdx.x * 32;
    const int k0 = blockIdx.y * 32;
    #pragma unroll
    for (int it = 0; it < 4; ++it) {
        int k = k0 + ty + it * 8;
        int n = n0 + tx;
        sh[ty + it * 8][tx] = (k < K && n < N) ? W[(size_t)k * N + n] : 0.f;
    }
    __syncthreads();
    #pragma unroll
    for (int it = 0; it < 4; ++it) {
        int n = n0 + ty + it * 8;
        int k = k0 + tx;
        float v = sh[tx][ty + it * 8];
        float s = sW[n];
        int q = __float2int_rn(v / s);
        q = min(max(q, -16256), 16256);
        int q1 = (q + 64) >> 7;
        int q2 = q - (q1 << 7);
        Wq1T[(size_t)n * K_PAD + k] = (signed char)q1;
        Wq2T[(size_t)n * K_PAD + k] = (signed char)q2;
    }
}

// ---------------- i8 MFMA GEMM: 3-term, 16x16x64 ----------------
// H = sA[m]*sW[n]*(16384*accH + 128*accM) + bias; OUTBF: 1 -> bf16 out, 0 -> f32.
// r10-verified schedule. launch_bounds(256,2): r13/r15-proven VGPR 104, zero spill.
// (256,3) caps the allocator below the 128-reg accumulator state -> spill (r14).

#define GBM 128
#define GBN 128

#define ISSUE2I(p0, p1, ss) do { \
    GLOAD_LDS16(p0, &lds[ss][wid * 1024]); \
    GLOAD_LDS16(p1, &lds[ss][wid * 1024 + 4096]); \
    p0 += 64; p1 += 64; } while (0)

template <int OUTBF>
__global__ __launch_bounds__(256, 2)
void gemm_i8_mfma_kernel(const signed char* __restrict__ Aq1,
                         const signed char* __restrict__ Aq2,
                         const signed char* __restrict__ Bq1T,
                         const signed char* __restrict__ Bq2T,
                         const float* __restrict__ sA, const float* __restrict__ sB,
                         const float* __restrict__ bias, void* __restrict__ Hout,
                         int K, int NB, int ldh, int nbias) {
    __shared__ __align__(16) char lds[4][8192];

    const int t    = threadIdx.x;
    const int wid  = t >> 6;
    const int lane = t & 63;
    const int wr   = wid >> 1;
    const int wc   = wid & 1;

    const int orig = blockIdx.x;
    const int nwg  = gridDim.x;
    const int xcd  = orig & 7, loc = orig >> 3;
    const int q    = nwg >> 3, r = nwg & 7;
    const int wgid = (xcd < r ? xcd * (q + 1) : r * (q + 1) + (xcd - r) * q) + loc;
    const int m0   = (wgid / NB) * GBM;
    const int n0   = (wgid % NB) * GBN;

    i32x4 accH[4][4] = {};
    i32x4 accM[4][4] = {};

    const int byt0 = wid * 1024 + lane * 16;
    const int byt1 = byt0 + 4096;
    const int r0 = byt0 >> 6, r1 = byt1 >> 6;
    const int cs0 = (byt0 & 63) ^ (((r0 >> 1) & 3) << 4);
    const int cs1 = (byt1 & 63) ^ (((r1 >> 1) & 3) << 4);

    const signed char* pA10 = Aq1  + (size_t)(m0 + r0) * K + cs0;
    const signed char* pA11 = Aq1  + (size_t)(m0 + r1) * K + cs1;
    const signed char* pA20 = Aq2  + (size_t)(m0 + r0) * K + cs0;
    const signed char* pA21 = Aq2  + (size_t)(m0 + r1) * K + cs1;
    const signed char* pB10 = Bq1T + (size_t)(n0 + r0) * K + cs0;
    const signed char* pB11 = Bq1T + (size_t)(n0 + r1) * K + cs1;
    const signed char* pB20 = Bq2T + (size_t)(n0 + r0) * K + cs0;
    const signed char* pB21 = Bq2T + (size_t)(n0 + r1) * K + cs1;

    const int fr   = lane & 15;
    const int kbs  = ((lane >> 4) << 4) ^ (((fr >> 1) & 3) << 4);
    const int arow = wr * 64;
    const int brow = wc * 64;

    ISSUE2I(pA10, pA11, 0);
    ISSUE2I(pB10, pB11, 2);
    ISSUE2I(pB20, pB21, 3);
    ISSUE2I(pA20, pA21, 1);

    const int NT = K >> 6;
    i32x4 a1[4], b1[4], b2[4], a2[4];

    for (int tt = 0; tt < NT; ++tt) {
        // ---- phase 1: A1*B1 -> accH ----
        if (tt == 0) asm volatile("s_waitcnt vmcnt(4)" ::: "memory");
        else         asm volatile("s_waitcnt vmcnt(2)" ::: "memory");
        __builtin_amdgcn_s_barrier();
        #pragma unroll
        for (int i = 0; i < 4; ++i)
            a1[i] = *(const i32x4*)(&lds[0][(arow + i * 16 + fr) * 64 + kbs]);
        #pragma unroll
        for (int j = 0; j < 4; ++j)
            b1[j] = *(const i32x4*)(&lds[2][(brow + j * 16 + fr) * 64 + kbs]);
        if (tt > 0) ISSUE2I(pA20, pA21, 1);
        __builtin_amdgcn_s_setprio(1);
        #pragma unroll
        for (int i = 0; i < 4; ++i)
            #pragma unroll
            for (int j = 0; j < 4; ++j)
                accH[i][j] = __builtin_amdgcn_mfma_i32_16x16x64_i8(a1[i], b1[j], accH[i][j], 0, 0, 0);
        __builtin_amdgcn_s_setprio(0);
        // ---- phase 2: A1*B2 -> accM ----
        asm volatile("s_waitcnt vmcnt(2)" ::: "memory");
        __builtin_amdgcn_s_barrier();
        #pragma unroll
        for (int j = 0; j < 4; ++j)
            b2[j] = *(const i32x4*)(&lds[3][(brow + j * 16 + fr) * 64 + kbs]);
        if (tt < NT - 1) {
            ISSUE2I(pA10, pA11, 0);
            ISSUE2I(pB10, pB11, 2);
        }
        __builtin_amdgcn_s_setprio(1);
        #pragma unroll
        for (int i = 0; i < 4; ++i)
            #pragma unroll
            for (int j = 0; j < 4; ++j)
                accM[i][j] = __builtin_amdgcn_mfma_i32_16x16x64_i8(a1[i], b2[j], accM[i][j], 0, 0, 0);
        __builtin_amdgcn_s_setprio(0);
        // ---- phase 3: A2*B1 -> accM ----
        if (tt < NT - 1) asm volatile("s_waitcnt vmcnt(4)" ::: "memory");
        else             asm volatile("s_waitcnt vmcnt(0)" ::: "memory");
        __builtin_amdgcn_s_barrier();
        #pragma unroll
        for (int i = 0; i < 4; ++i)
            a2[i] = *(const i32x4*)(&lds[1][(arow + i * 16 + fr) * 64 + kbs]);
        if (tt < NT - 1) ISSUE2I(pB20, pB21, 3);
        __builtin_amdgcn_s_setprio(1);
        #pragma unroll
        for (int i = 0; i < 4; ++i)
            #pragma unroll
            for (int j = 0; j < 4; ++j)
                accM[i][j] = __builtin_amdgcn_mfma_i32_16x16x64_i8(a2[i], b1[j], accM[i][j], 0, 0, 0);
        __builtin_amdgcn_s_setprio(0);
    }

    // epilogue: C layout col = lane&15, row = (lane>>4)*4 + reg
    #pragma unroll
    for (int i = 0; i < 4; ++i) {
        #pragma unroll
        for (int j = 0; j < 4; ++j) {
            int row = m0 + wr * 64 + i * 16 + (lane >> 4) * 4;
            int col = n0 + wc * 64 + j * 16 + (lane & 15);
            float bv = (col < nbias) ? bias[col] : 0.f;
            float sw = sB[col];
            #pragma unroll
            for (int r2 = 0; r2 < 4; ++r2) {
                float sa = sA[row + r2];
                float v = sa * sw * (16384.f * (float)accH[i][j][r2] + 128.f * (float)accM[i][j][r2]) + bv;
                if (OUTBF) ((unsigned short*)Hout)[(size_t)(row + r2) * ldh + col] = f2bf(v);
                else       ((float*)Hout)[(size_t)(row + r2) * ldh + col] = v;
            }
        }
    }
}

// ---------------- fp32 tiled GEMM (fallback path only) ----------------

#define BM 64
#define BN 64
#define BKT 16
#define TM 4
#define TN 4

__global__ __launch_bounds__(256)
void gemm_bias_kernel(const float* __restrict__ X, const float* __restrict__ W,
                      const float* __restrict__ bias, float* __restrict__ H,
                      int M, int N, int K) {
    __shared__ float As[BKT][BM];
    __shared__ float Bs[BKT][BN];

    const int t  = threadIdx.x;
    const int tx = t & 15;
    const int ty = t >> 4;
    const int m0 = blockIdx.y * BM;
    const int n0 = blockIdx.x * BN;

    float acc[TM][TN] = {};

    const int arow = t >> 2;
    const int ak0  = (t & 3) * 4;
    const int brow = t >> 4;
    const int bn0  = (t & 15) * 4;

    for (int k0 = 0; k0 < K; k0 += BKT) {
        {
            float4 v = make_float4(0.f, 0.f, 0.f, 0.f);
            int gm = m0 + arow;
            int gk = k0 + ak0;
            if (gm < M) {
                if (gk + 3 < K) {
                    v = *reinterpret_cast<const float4*>(&X[(long)gm * K + gk]);
                } else {
                    float tmp[4] = {0.f, 0.f, 0.f, 0.f};
                    for (int i = 0; i < 4; ++i)
                        if (gk + i < K) tmp[i] = X[(long)gm * K + gk + i];
                    v = make_float4(tmp[0], tmp[1], tmp[2], tmp[3]);
                }
            }
            As[ak0 + 0][arow] = v.x;
            As[ak0 + 1][arow] = v.y;
            As[ak0 + 2][arow] = v.z;
            As[ak0 + 3][arow] = v.w;
        }
        {
            float4 v = make_float4(0.f, 0.f, 0.f, 0.f);
            int gk = k0 + brow;
            int gn = n0 + bn0;
            if (gk < K) {
                if (gn + 3 < N) {
                    v = *reinterpret_cast<const float4*>(&W[(long)gk * N + gn]);
                } else {
                    float tmp[4] = {0.f, 0.f, 0.f, 0.f};
                    for (int i = 0; i < 4; ++i)
                        if (gn + i < N) tmp[i] = W[(long)gk * N + gn + i];
                    v = make_float4(tmp[0], tmp[1], tmp[2], tmp[3]);
                }
            }
            *reinterpret_cast<float4*>(&Bs[brow][bn0]) = v;
        }
        __syncthreads();

        #pragma unroll
        for (int kk = 0; kk < BKT; ++kk) {
            float a[TM], b[TN];
            *reinterpret_cast<float4*>(a) = *reinterpret_cast<const float4*>(&As[kk][ty * TM]);
            *reinterpret_cast<float4*>(b) = *reinterpret_cast<const float4*>(&Bs[kk][tx * TN]);
            #pragma unroll
            for (int i = 0; i < TM; ++i)
                #pragma unroll
                for (int j = 0; j < TN; ++j)
                    acc[i][j] += a[i] * b[j];
        }
        __syncthreads();
    }

    #pragma unroll
    for (int i = 0; i < TM; ++i) {
        int gm = m0 + ty * TM + i;
        if (gm >= M) continue;
        #pragma unroll
        for (int j = 0; j < TN; ++j) {
            int gn = n0 + tx * TN + j;
            if (gn < N) H[(long)gm * N + gn] = acc[i][j] + bias[gn];
        }
    }
}

// ---------------- aggregates ----------------

// layer-1 aggregate: reads bf16 H1, relu, fused i8 quantize (block-max scheme)
__global__ __launch_bounds__(256)
void aggregate_i8_kernel(const unsigned short* __restrict__ H1,
                         const int* __restrict__ row_start, const int* __restrict__ esrc,
                         signed char* __restrict__ Xq1, signed char* __restrict__ Xq2,
                         float* __restrict__ sX, int d, int ld_in, int kpad) {
    __shared__ float red[256];
    const int node = blockIdx.x;
    const int t = threadIdx.x;
    const int f = t * 4;
    const int beg = row_start[node];
    const int end = row_start[node + 1];

    float a[4] = {0.f, 0.f, 0.f, 0.f};
    if (f < d) {
        ushort4 v = *reinterpret_cast<const ushort4*>(&H1[(size_t)node * ld_in + f]);
        a[0] = bf2f(v.x); a[1] = bf2f(v.y); a[2] = bf2f(v.z); a[3] = bf2f(v.w);
        for (int i = beg; i < end; ++i) {
            ushort4 w = *reinterpret_cast<const ushort4*>(&H1[(size_t)esrc[i] * ld_in + f]);
            a[0] += bf2f(w.x); a[1] += bf2f(w.y); a[2] += bf2f(w.z); a[3] += bf2f(w.w);
        }
        a[0] = fmaxf(a[0], 0.f); a[1] = fmaxf(a[1], 0.f);
        a[2] = fmaxf(a[2], 0.f); a[3] = fmaxf(a[3], 0.f);
    }
    float mx = fmaxf(fmaxf(a[0], a[1]), fmaxf(a[2], a[3]));
    red[t] = mx;
    __syncthreads();
    for (int off = 128; off > 0; off >>= 1) {
        if (t < off) red[t] = fmaxf(red[t], red[t + off]);
        __syncthreads();
    }
    const float rmax = red[0];
    const float s   = (rmax > 0.f) ? rmax / 16256.f : 1.f;
    const float inv = 16256.f / ((rmax > 0.f) ? rmax : 1.f);
    if (t == 0) sX[node] = s;
    if (f < kpad) {
        signed char q1v[4], q2v[4];
        #pragma unroll
        for (int e = 0; e < 4; ++e) {
            int q = (f < d) ? __float2int_rn(a[e] * inv) : 0;
            q = min(max(q, 0), 16256);
            int q1 = (q + 64) >> 7;
            int q2 = q - (q1 << 7);
            q1v[e] = (signed char)q1; q2v[e] = (signed char)q2;
        }
        *reinterpret_cast<char4*>(&Xq1[(size_t)node * kpad + f]) = make_char4(q1v[0], q1v[1], q1v[2], q1v[3]);
        *reinterpret_cast<char4*>(&Xq2[(size_t)node * kpad + f]) = make_char4(q2v[0], q2v[1], q2v[2], q2v[3]);
    }
}

// fused: x3 = relu(agg(H2 bf16, d=300)) in LDS; h3 = x3 @ W3[300,20] + b3
__global__ __launch_bounds__(128)
void agg2_gemm3_kernel(const unsigned short* __restrict__ H2, const int* __restrict__ row_start,
                       const int* __restrict__ esrc, const float* __restrict__ W3,
                       const float* __restrict__ b3, float* __restrict__ h3) {
    __shared__ float x3s[304];
    __shared__ float part[6][20];
    const int node = blockIdx.x;
    const int t = threadIdx.x;
    const int beg = row_start[node];
    const int end = row_start[node + 1];
    if (t < 75) {
        const int f = t * 4;
        ushort4 v = *reinterpret_cast<const ushort4*>(&H2[(size_t)node * LDH2 + f]);
        float a0 = bf2f(v.x), a1 = bf2f(v.y), a2 = bf2f(v.z), a3 = bf2f(v.w);
        for (int i = beg; i < end; ++i) {
            ushort4 w = *reinterpret_cast<const ushort4*>(&H2[(size_t)esrc[i] * LDH2 + f]);
            a0 += bf2f(w.x); a1 += bf2f(w.y); a2 += bf2f(w.z); a3 += bf2f(w.w);
        }
        x3s[f + 0] = fmaxf(a0, 0.f);
        x3s[f + 1] = fmaxf(a1, 0.f);
        x3s[f + 2] = fmaxf(a2, 0.f);
        x3s[f + 3] = fmaxf(a3, 0.f);
    }
    __syncthreads();
    if (t < 120) {
        const int j = t % 20, g = t / 20;
        float s = 0.f;
        #pragma unroll 5
        for (int k = g * 50; k < g * 50 + 50; ++k)
            s += x3s[k] * W3[k * 20 + j];
        part[g][j] = s;
    }
    __syncthreads();
    if (t < 20) {
        float s = b3[t];
        #pragma unroll
        for (int g = 0; g < 6; ++g) s += part[g][t];
        h3[(size_t)node * 20 + t] = s;
    }
}

// fused: x4 = agg(h3, d=20) in LDS; h4 = x4 @ W4[20,10] + b4
__global__ __launch_bounds__(64)
void agg3_gemm4_kernel(const float* __restrict__ h3, const int* __restrict__ row_start,
                       const int* __restrict__ esrc, const float* __restrict__ W4,
                       const float* __restrict__ b4, float* __restrict__ h4) {
    __shared__ float x4s[20];
    const int node = blockIdx.x;
    const int t = threadIdx.x;
    const int beg = row_start[node];
    const int end = row_start[node + 1];
    if (t < 20) {
        float acc = h3[(size_t)node * 20 + t];
        for (int i = beg; i < end; ++i)
            acc += h3[(size_t)esrc[i] * 20 + t];
        x4s[t] = acc;
    }
    __syncthreads();
    if (t < 10) {
        float s = b4[t];
        #pragma unroll
        for (int k = 0; k < 20; ++k) s += x4s[k] * W4[k * 10 + t];
        h4[(size_t)node * 10 + t] = s;
    }
}

template <int ACT>
__global__ __launch_bounds__(64)
void aggregate_small_kernel(const float* __restrict__ H, const int* __restrict__ row_start,
                            const int* __restrict__ esrc, float* __restrict__ out,
                            int d, int ld_in, int ld_out) {
    const int node = blockIdx.x;
    const int f = threadIdx.x;
    if (f >= d) return;
    const int beg = row_start[node];
    const int end = row_start[node + 1];
    float acc = H[(size_t)node * ld_in + f];
    for (int i = beg; i < end; ++i)
        acc += H[(size_t)esrc[i] * ld_in + f];
    if (ACT == 1) acc = fmaxf(acc, 0.f);
    if (ACT == 2) acc = tanhf(acc);
    out[(size_t)node * ld_out + f] = acc;
}

template <int ACT>
__global__ __launch_bounds__(256)
void aggregate_kernel(const float* __restrict__ H, const int* __restrict__ row_start,
                      const int* __restrict__ esrc, float* __restrict__ out,
                      int d, int ld_in) {
    const int node = blockIdx.x;
    const int t = threadIdx.x;
    const int beg = row_start[node];
    const int end = row_start[node + 1];
    float acc[4] = {0.f, 0.f, 0.f, 0.f};
    #pragma unroll
    for (int j = 0; j < 4; ++j) {
        int f = t + j * 256;
        if (f < d) acc[j] = H[(size_t)node * ld_in + f];
    }
    for (int i = beg; i < end; ++i) {
        const size_t b = (size_t)esrc[i] * ld_in;
        #pragma unroll
        for (int j = 0; j < 4; ++j) {
            int f = t + j * 256;
            if (f < d) acc[j] += H[b + f];
        }
    }
    #pragma unroll
    for (int j = 0; j < 4; ++j) {
        int f = t + j * 256;
        if (f < d) {
            float v = acc[j];
            if (ACT == 1) v = fmaxf(v, 0.f);
            if (ACT == 2) v = tanhf(v);
            out[(size_t)node * d + f] = v;
        }
    }
}

// ---------------- launch ----------------

extern "C" void kernel_launch(void* const* d_in, const int* in_sizes, int n_in,
                              void* d_out, int out_size, void* d_ws, size_t ws_size,
                              hipStream_t stream) {
    const float* features = (const float*)d_in[0];
    const int*   src      = (const int*)d_in[1];
    const int*   dst      = (const int*)d_in[2];
    const float* W1 = (const float*)d_in[3];  const float* b1 = (const float*)d_in[4];
    const float* W2 = (const float*)d_in[5];  const float* b2 = (const float*)d_in[6];
    const float* W3 = (const float*)d_in[7];  const float* b3 = (const float*)d_in[8];
    const float* W4 = (const float*)d_in[9];  const float* b4 = (const float*)d_in[10];
    float* out = (float*)d_out;
    char* ws = (char*)d_ws;

    // ---- workspace map (~174 MB) ----
    const size_t SZ_AQ    = (size_t)M_PAD * D_IN;
    const size_t OFF_AQ1  = 0;
    const size_t OFF_AQ2  = SZ_AQ;
    const size_t OFF_H1   = 2 * SZ_AQ;
    const size_t SZ_H1    = (size_t)M_PAD * LDH1 * 2;       // bf16
    const size_t OFF_W1Q1 = OFF_H1 + SZ_H1;
    const size_t SZ_W1Q   = (size_t)N1_PAD * D_IN;
    const size_t OFF_W1Q2 = OFF_W1Q1 + SZ_W1Q;
    const size_t OFF_SA   = OFF_W1Q2 + SZ_W1Q;
    const size_t SZ_SA    = (size_t)M_PAD * 4;
    const size_t OFF_SW1  = OFF_SA + SZ_SA;
    const size_t OFF_W2Q1 = OFF_SW1 + 4096;
    const size_t SZ_W2Q   = (size_t)N2_PAD * K2_PAD;
    const size_t OFF_W2Q2 = OFF_W2Q1 + SZ_W2Q;
    const size_t OFF_SW2  = OFF_W2Q2 + SZ_W2Q;
    const size_t OFF_SA2  = OFF_SW2 + 4096;
    const size_t OFF_CSR  = OFF_SA2 + SZ_SA;
    const size_t SZ_CSR   = (size_t)(N_NODES * 3 + 1 + N_EDGES) * 4;
    const size_t WS_NEED  = OFF_CSR + SZ_CSR;

    const size_t OFF_X2Q1 = 0;
    const size_t SZ_X2Q   = (size_t)M_PAD * K2_PAD;
    const size_t OFF_X2Q2 = SZ_X2Q;
    const size_t OFF_H2   = 2 * SZ_X2Q;                     // bf16 H2
    const size_t OFF_H3   = OFF_H1;
    const size_t OFF_H4   = OFF_H1 + 1600000;

    const bool use_mfma = (ws_size >= WS_NEED);
    size_t csr_off = use_mfma ? OFF_CSR : (size_t)2 * N_NODES * 1000 * 4;
    int* counts    = (int*)(ws + csr_off);
    int* row_start = counts + N_NODES;
    int* cursor    = row_start + N_NODES + 1;
    int* esrc      = cursor + N_NODES;

    zero_counts_kernel<<<(N_NODES + 255) / 256, 256, 0, stream>>>(counts);
    count_kernel<<<(N_EDGES + 255) / 256, 256, 0, stream>>>(dst, counts);
    scan_kernel<<<1, 1024, 0, stream>>>(counts, row_start, cursor);
    scatter_kernel<<<(N_EDGES + 255) / 256, 256, 0, stream>>>(src, dst, cursor, esrc);

    if (use_mfma) {
        signed char*    Aq1   = (signed char*)(ws + OFF_AQ1);
        signed char*    Aq2   = (signed char*)(ws + OFF_AQ2);
        unsigned short* H1    = (unsigned short*)(ws + OFF_H1);
        signed char*    W1q1T = (signed char*)(ws + OFF_W1Q1);
        signed char*    W1q2T = (signed char*)(ws + OFF_W1Q2);
        float*          sA    = (float*)(ws + OFF_SA);
        float*          sW1   = (float*)(ws + OFF_SW1);
        unsigned*       sW1b  = (unsigned*)(ws + OFF_SW1);
        signed char*    W2q1T = (signed char*)(ws + OFF_W2Q1);
        signed char*    W2q2T = (signed char*)(ws + OFF_W2Q2);
        float*          sW2   = (float*)(ws + OFF_SW2);
        unsigned*       sW2b  = (unsigned*)(ws + OFF_SW2);
        signed char*    X2q1  = (signed char*)(ws + OFF_X2Q1);
        signed char*    X2q2  = (signed char*)(ws + OFF_X2Q2);
        float*          sA2   = (float*)(ws + OFF_SA2);
        unsigned short* H2    = (unsigned short*)(ws + OFF_H2);
        float*          h3    = (float*)(ws + OFF_H3);
        float*          h4    = (float*)(ws + OFF_H4);

        // Layer 1: i8 3-term MFMA GEMM (16x16x64), bf16 H1 out
        convA_i8_kernel<<<N_NODES, 256, 0, stream>>>(features, Aq1, Aq2, sA);
        zero_swbits_kernel<<<N1_PAD / 256, 256, 0, stream>>>(sW1b, N1_PAD);
        colmaxW_kernel<<<dim3((1000 + 255) / 256, 24), 256, 0, stream>>>(W1, sW1b, D_IN, 1000, 128);
        finalize_sw_kernel<<<N1_PAD / 256, 256, 0, stream>>>(sW1b, sW1, N1_PAD);
        convW_i8_kernel<<<dim3(N1_PAD / 32, D_IN / 32), 256, 0, stream>>>(
            W1, sW1, W1q1T, W1q2T, D_IN, 1000, D_IN);
        gemm_i8_mfma_kernel<1><<<(N1_PAD / GBN) * (M_PAD / GBM), 256, 0, stream>>>(
            Aq1, Aq2, W1q1T, W1q2T, sA, sW1, b1, H1, D_IN, N1_PAD / GBN, LDH1, 1000);
        aggregate_i8_kernel<<<N_NODES, 256, 0, stream>>>(
            H1, row_start, esrc, X2q1, X2q2, sA2, 1000, LDH1, K2_PAD);

        // Layer 2: i8 3-term MFMA GEMM, bf16 H2 out
        zero_swbits_kernel<<<(N2_PAD + 255) / 256, 256, 0, stream>>>(sW2b, N2_PAD);
        colmaxW_kernel<<<dim3((300 + 255) / 256, 8), 256, 0, stream>>>(W2, sW2b, 1000, 300, 128);
        finalize_sw_kernel<<<(N2_PAD + 255) / 256, 256, 0, stream>>>(sW2b, sW2, N2_PAD);
        convW_i8_kernel<<<dim3(N2_PAD / 32, K2_PAD / 32), 256, 0, stream>>>(
            W2, sW2, W2q1T, W2q2T, 1000, 300, K2_PAD);
        gemm_i8_mfma_kernel<1><<<(N2_PAD / GBN) * (M_PAD / GBM), 256, 0, stream>>>(
            X2q1, X2q2, W2q1T, W2q2T, sA2, sW2, b2, H2, K2_PAD, N2_PAD / GBN, LDH2, 300);

        // Layers 3+4 fused
        agg2_gemm3_kernel<<<N_NODES, 128, 0, stream>>>(H2, row_start, esrc, W3, b3, h3);
        agg3_gemm4_kernel<<<N_NODES, 64, 0, stream>>>(h3, row_start, esrc, W4, b4, h4);
        aggregate_small_kernel<2><<<N_NODES, 64, 0, stream>>>(h4, row_start, esrc, out, 10, 10, 10);
    } else {
        const size_t BUF = (size_t)N_NODES * 1000 * 4;
        float* bufA = (float*)ws;
        float* bufB = (float*)(ws + BUF);

        dim3 g1((1000 + BN - 1) / BN, (N_NODES + BM - 1) / BM);
        gemm_bias_kernel<<<g1, 256, 0, stream>>>(features, W1, b1, bufA, N_NODES, 1000, D_IN);
        aggregate_kernel<1><<<N_NODES, 256, 0, stream>>>(bufA, row_start, esrc, bufB, 1000, 1000);

        dim3 g2((300 + BN - 1) / BN, (N_NODES + BM - 1) / BM);
        gemm_bias_kernel<<<g2, 256, 0, stream>>>(bufB, W2, b2, bufA, N_NODES, 300, 1000);
        aggregate_kernel<1><<<N_NODES, 256, 0, stream>>>(bufA, row_start, esrc, bufB, 300, 300);

        dim3 g3((20 + BN - 1) / BN, (N_NODES + BM - 1) / BM);
        gemm_bias_kernel<<<g3, 256, 0, stream>>>(bufB, W3, b3, bufA, N_NODES, 20, 300);
        aggregate_kernel<0><<<N_NODES, 256, 0, stream>>>(bufA, row_start, esrc, bufB, 20, 20);

        dim3 g4((10 + BN - 1) / BN, (N_NODES + BM - 1) / BM);
        gemm_bias_kernel<<<g4, 256, 0, stream>>>(bufB, W4, b4, bufA, N_NODES, 10, 20);
        aggregate_kernel<2><<<N_NODES, 256, 0, stream>>>(bufA, row_start, esrc, out, 10, 10);
    }
}